// Round 4
// baseline (415.492 us; speedup 1.0000x reference)
//
#include <hip/hip_runtime.h>
#include <cmath>

// LoRAAttention, MI355X round 4.
//  - LoRA folded into effective weights (exact).
//  - QKV/proj GEMMs: double-buffered async LDS staging, ONE barrier per K-iter
//    (prefetch issued post-barrier, drained at the next barrier -> overlaps
//    compute). Operand-swapped MFMA for q/k/proj so the C-layout packs the
//    contiguous output axis into reg index r -> 8B/16B packed stores.
//  - Attention (round-3 design): 128-row Q tiles, P in registers via
//    C-layout == half-K A-layout identity, l-sum via ones-column MFMA,
//    native v_exp_f32, async double-buffered K/V^T staging.

#define DEVI __device__ __forceinline__

typedef float f32x4 __attribute__((ext_vector_type(4)));
typedef short s16x8 __attribute__((ext_vector_type(8)));
typedef __bf16 b16x8 __attribute__((ext_vector_type(8)));
typedef unsigned int u32x4 __attribute__((ext_vector_type(4)));

static constexpr int MTOT = 16384;   // B*N
static constexpr int C = 768;
static constexpr int N3 = 2304;

DEVI unsigned short f2bf(float x) {
  unsigned int u = __builtin_bit_cast(unsigned int, x);
  return (unsigned short)((u + 0x7FFFu + ((u >> 16) & 1u)) >> 16);
}

DEVI f32x4 mfma16(s16x8 a, s16x8 b, f32x4 c) {
  return __builtin_amdgcn_mfma_f32_16x16x32_bf16(
      __builtin_bit_cast(b16x8, a), __builtin_bit_cast(b16x8, b), c, 0, 0, 0);
}

DEVI void async16(const void* g, void* l) {
  __builtin_amdgcn_global_load_lds(
      (__attribute__((address_space(1))) void*)g,
      (__attribute__((address_space(3))) void*)l, 16, 0, 0);
}

// ---------------- prep kernels ----------------

__global__ __launch_bounds__(256) void k_prep_x(const float* __restrict__ x,
                                                unsigned short* __restrict__ xb) {
  int idx = (blockIdx.x * 256 + threadIdx.x) * 4;
  float4 v = *(const float4*)(x + idx);
  uint2 p;
  p.x = (unsigned int)f2bf(v.x) | ((unsigned int)f2bf(v.y) << 16);
  p.y = (unsigned int)f2bf(v.z) | ((unsigned int)f2bf(v.w) << 16);
  *(uint2*)(xb + idx) = p;
}

__global__ __launch_bounds__(256) void k_prep_wqkv(
    const float* __restrict__ W, const float* __restrict__ Aq,
    const float* __restrict__ Bq, const float* __restrict__ Ak,
    const float* __restrict__ Bk, const float* __restrict__ Av,
    const float* __restrict__ Bv, unsigned short* __restrict__ out) {
  int idx = blockIdx.x * 256 + threadIdx.x;  // n*768 + c
  int n = idx / 768, c = idx - n * 768;
  int s = n / 768, co = n - s * 768;
  const float* A = (s == 0) ? Aq : (s == 1) ? Ak : Av;
  const float* Bm = (s == 0) ? Bq : (s == 1) ? Bk : Bv;
  float acc = W[idx];
#pragma unroll
  for (int r = 0; r < 16; ++r) acc += Bm[co * 16 + r] * A[r * 768 + c];
  out[idx] = f2bf(acc);
}

// M[r][j] = sum_c Ao[r][c] * Wp[c][j]
__global__ __launch_bounds__(256) void k_prep_M(const float* __restrict__ Ao,
                                                const float* __restrict__ Wp,
                                                float* __restrict__ M) {
  int r = blockIdx.x, t = threadIdx.x;
  float a0 = 0.f, a1 = 0.f, a2 = 0.f;
  for (int c = 0; c < 768; ++c) {
    float a = Ao[r * 768 + c];
    a0 += a * Wp[c * 768 + t];
    a1 += a * Wp[c * 768 + t + 256];
    a2 += a * Wp[c * 768 + t + 512];
  }
  M[r * 768 + t] = a0;
  M[r * 768 + t + 256] = a1;
  M[r * 768 + t + 512] = a2;
}

__global__ __launch_bounds__(256) void k_prep_wpe(const float* __restrict__ Wp,
                                                  const float* __restrict__ Bo,
                                                  const float* __restrict__ M,
                                                  unsigned short* __restrict__ out) {
  int idx = blockIdx.x * 256 + threadIdx.x;  // n*768 + j
  int n = idx / 768, j = idx - n * 768;
  float acc = Wp[idx];
#pragma unroll
  for (int r = 0; r < 16; ++r) acc += Bo[n * 16 + r] * M[r * 768 + j];
  out[idx] = f2bf(acc);
}

__global__ __launch_bounds__(256) void k_prep_beff(const float* __restrict__ bp,
                                                   const float* __restrict__ Ao,
                                                   const float* __restrict__ Bo,
                                                   float* __restrict__ beff) {
  __shared__ float bv[16];
  int t = threadIdx.x;
  if (t < 16) {
    float a0 = 0.f, a1 = 0.f, a2 = 0.f;
    for (int c = 0; c < 256; ++c) {
      a0 += Ao[t * 768 + c] * bp[c];
      a1 += Ao[t * 768 + c + 256] * bp[c + 256];
      a2 += Ao[t * 768 + c + 512] * bp[c + 512];
    }
    bv[t] = a0 + a1 + a2;
  }
  __syncthreads();
  int n = blockIdx.x * 256 + t;
  float acc = bp[n];
#pragma unroll
  for (int r = 0; r < 16; ++r) acc += Bo[n * 16 + r] * bv[r];
  beff[n] = acc;
}

// ---------------- QKV GEMM: [16384,768] x [2304,768]^T -> q/k/vt bf16 --------
// Launched twice: SWAP=true for q/k n-blocks (packed d-stores), SWAP=false for
// v n-blocks (transposed [bh][d][pos] stores). One barrier per K-iter (dbuf).

template <bool SWAP>
__global__ __launch_bounds__(256) void k_gemm_qkv_t(
    const unsigned short* __restrict__ A, const unsigned short* __restrict__ Bw,
    const float* __restrict__ bias, int nblk0, unsigned short* __restrict__ qb,
    unsigned short* __restrict__ kb, unsigned short* __restrict__ vtb) {
  __shared__ short la[2][128 * 32];
  __shared__ short lb[2][128 * 32];
  const int t = threadIdx.x;
  const int w = t >> 6, l = t & 63;
  const int i = l & 15, qd = l >> 4;
  const int wm = w >> 1, wn = w & 1;
  const int mblk = blockIdx.x, nblk = nblk0 + blockIdx.y;

  const unsigned short* Ab = A + (size_t)(mblk * 128) * 768;
  const unsigned short* Bb = Bw + (size_t)(nblk * 128) * 768;
  const int sr = l >> 2;        // 0..15
  const int sc = (l & 3) * 8;   // 0,8,16,24

  auto stage = [&](int bufn, int kb_) {
    const int k0 = kb_ * 32;
#pragma unroll
    for (int j = 0; j < 2; ++j) {
      const int row = w * 32 + j * 16 + sr;
      async16(Ab + row * 768 + k0 + sc, &la[bufn][(w * 32 + j * 16) * 32]);
      async16(Bb + row * 768 + k0 + sc, &lb[bufn][(w * 32 + j * 16) * 32]);
    }
  };

  stage(0, 0);

  f32x4 acc[4][4] = {};

  for (int kb_ = 0; kb_ < 24; ++kb_) {
    const int buf = kb_ & 1;
    __syncthreads();
    if (kb_ < 23) stage(buf ^ 1, kb_ + 1);
    s16x8 af[4], bf[4];
#pragma unroll
    for (int mi = 0; mi < 4; ++mi)
      af[mi] = *(const s16x8*)&la[buf][(wm * 64 + mi * 16 + i) * 32 + qd * 8];
#pragma unroll
    for (int ni = 0; ni < 4; ++ni)
      bf[ni] = *(const s16x8*)&lb[buf][(wn * 64 + ni * 16 + i) * 32 + qd * 8];
#pragma unroll
    for (int mi = 0; mi < 4; ++mi)
#pragma unroll
      for (int ni = 0; ni < 4; ++ni) {
        if constexpr (SWAP)
          acc[mi][ni] = mfma16(bf[ni], af[mi], acc[mi][ni]);
        else
          acc[mi][ni] = mfma16(af[mi], bf[ni], acc[mi][ni]);
      }
  }

  const float c1 = 0.18033688011112042f;  // SCALE * log2(e)
  if constexpr (SWAP) {
    // q/k: lane i -> x-row (pos), reg r -> weight col (d): pack 4 d into 8B
#pragma unroll
    for (int ni = 0; ni < 4; ++ni) {
      const int n0 = nblk * 128 + wn * 64 + ni * 16 + qd * 4;
      const int s = n0 / 768;
      const int nrel = n0 - s * 768;
      const int h = nrel >> 6, d0 = nrel & 63;
      const float4 bv4 = *(const float4*)(bias + n0);
      unsigned short* dst = (s == 0) ? qb : kb;
      const float scl = (s == 0) ? c1 : 1.0f;
#pragma unroll
      for (int mi = 0; mi < 4; ++mi) {
        const int m = mblk * 128 + wm * 64 + mi * 16 + i;
        const int b = m >> 10, pos = m & 1023;
        uint2 pk;
        pk.x = (unsigned int)f2bf((acc[mi][ni][0] + bv4.x) * scl) |
               ((unsigned int)f2bf((acc[mi][ni][1] + bv4.y) * scl) << 16);
        pk.y = (unsigned int)f2bf((acc[mi][ni][2] + bv4.z) * scl) |
               ((unsigned int)f2bf((acc[mi][ni][3] + bv4.w) * scl) << 16);
        *(uint2*)&dst[(size_t)((b * 12 + h) * 1024 + pos) * 64 + d0] = pk;
      }
    }
  } else {
    // v: lane i -> weight col (d), reg r -> x-row (pos): transposed pack
#pragma unroll
    for (int ni = 0; ni < 4; ++ni) {
      const int n = nblk * 128 + wn * 64 + ni * 16 + i;
      const int nrel = n - 1536;
      const int h = nrel >> 6, d = nrel & 63;
      const float bvv = bias[n];
#pragma unroll
      for (int mi = 0; mi < 4; ++mi) {
        const int m0 = mblk * 128 + wm * 64 + mi * 16 + qd * 4;
        const int b = m0 >> 10, pos0 = m0 & 1023;
        uint2 pk;
        pk.x = (unsigned int)f2bf(acc[mi][ni][0] + bvv) |
               ((unsigned int)f2bf(acc[mi][ni][1] + bvv) << 16);
        pk.y = (unsigned int)f2bf(acc[mi][ni][2] + bvv) |
               ((unsigned int)f2bf(acc[mi][ni][3] + bvv) << 16);
        *(uint2*)&vtb[(size_t)((b * 12 + h) * 64 + d) * 1024 + pos0] = pk;
      }
    }
  }
}

// ---------------- flash attention (round-3 design) ----------------
// grid: (192 bh, 8 q-tiles of 128 rows), 256 threads (4 waves x 32 q-rows).

__global__ __launch_bounds__(256, 4) void k_attn(
    const unsigned short* __restrict__ qg, const unsigned short* __restrict__ kg,
    const unsigned short* __restrict__ vtg, unsigned short* __restrict__ og) {
  __shared__ short k_lds[2][64 * 64];
  __shared__ short vt_lds[2][64 * 64];

  const int t = threadIdx.x;
  const int w = t >> 6, l = t & 63;
  const int i = l & 15, qd = l >> 4;
  const int ix7 = l & 7;
  const int bh = blockIdx.x;    // 0..191 (fastest -> same-bh tiles share XCD)
  const int qblk = blockIdx.y;  // 0..7
  const int h = bh % 12, b = bh / 12;

  const unsigned short* Qg = qg + (size_t)(bh * 1024 + qblk * 128) * 64;
  const unsigned short* Kg = kg + (size_t)bh * 1024 * 64;
  const unsigned short* Vtg = vtg + (size_t)bh * 64 * 1024;

  const int srl = l >> 3;            // row-local 0..7
  const int sgc = (l & 7) ^ srl;     // swizzled global chunk 0..7

  s16x8 qf[2][2];
#pragma unroll
  for (int nq = 0; nq < 2; ++nq)
#pragma unroll
    for (int k0 = 0; k0 < 2; ++k0)
      qf[nq][k0] =
          *(const s16x8*)(Qg + (w * 32 + nq * 16 + i) * 64 + k0 * 32 + qd * 8);

  auto stage = [&](int bufn, int tkv) {
#pragma unroll
    for (int it = 0; it < 2; ++it) {
      const int rbase = it * 32 + w * 8;
      async16(Kg + (size_t)(tkv * 64 + rbase + srl) * 64 + sgc * 8,
              &k_lds[bufn][rbase * 64]);
      async16(Vtg + (size_t)(rbase + srl) * 1024 + tkv * 64 + sgc * 8,
              &vt_lds[bufn][rbase * 64]);
    }
  };

  stage(0, 0);

  f32x4 oacc[2][4] = {};  // [mq][nd], C-layout
  f32x4 lacc[2] = {};     // [mq], same C-layout rows as oacc
  const u32x4 ones_u = {0x3F803F80u, 0x3F803F80u, 0u, 0u};  // bf16 1.0 x4, hi 0
  const s16x8 ones = __builtin_bit_cast(s16x8, ones_u);

  for (int tkv = 0; tkv < 16; ++tkv) {
    const int buf = tkv & 1;
    __syncthreads();
    if (tkv < 15) stage(buf ^ 1, tkv + 1);

#pragma unroll
    for (int mi = 0; mi < 4; ++mi) {
      f32x4 st[2] = {};
#pragma unroll
      for (int k0 = 0; k0 < 2; ++k0) {
        const s16x8 kf = *(const s16x8*)&k_lds[buf][(mi * 16 + i) * 64 +
                                                    (((k0 * 4 + qd) ^ ix7) * 8)];
        st[0] = mfma16(kf, qf[0][k0], st[0]);
        st[1] = mfma16(kf, qf[1][k0], st[1]);
      }

      s16x8 pa[2];
#pragma unroll
      for (int mq = 0; mq < 2; ++mq) {
        unsigned int u0 = __builtin_bit_cast(
            unsigned int, __builtin_amdgcn_exp2f(st[mq][0]));
        unsigned int u1 = __builtin_bit_cast(
            unsigned int, __builtin_amdgcn_exp2f(st[mq][1]));
        unsigned int u2 = __builtin_bit_cast(
            unsigned int, __builtin_amdgcn_exp2f(st[mq][2]));
        unsigned int u3 = __builtin_bit_cast(
            unsigned int, __builtin_amdgcn_exp2f(st[mq][3]));
        u32x4 p;
        p[0] = __builtin_amdgcn_perm(u1, u0, 0x07060302u);
        p[1] = __builtin_amdgcn_perm(u3, u2, 0x07060302u);
        p[2] = 0u;
        p[3] = 0u;
        pa[mq] = __builtin_bit_cast(s16x8, p);
      }

#pragma unroll
      for (int nd = 0; nd < 4; ++nd) {
        const uint2 v = *(const uint2*)&vt_lds[buf][(nd * 16 + i) * 64 +
                                                    ((((mi * 2 + (qd >> 1)) ^ ix7) * 8) +
                                                     (qd & 1) * 4)];
        u32x4 vu = {v.x, v.y, 0u, 0u};
        const s16x8 vf = __builtin_bit_cast(s16x8, vu);
        oacc[0][nd] = mfma16(pa[0], vf, oacc[0][nd]);
        oacc[1][nd] = mfma16(pa[1], vf, oacc[1][nd]);
      }
      lacc[0] = mfma16(pa[0], ones, lacc[0]);
      lacc[1] = mfma16(pa[1], ones, lacc[1]);
    }
  }

  const int orow0 = qblk * 128 + w * 32;
#pragma unroll
  for (int mq = 0; mq < 2; ++mq) {
    float linv[4];
#pragma unroll
    for (int r = 0; r < 4; ++r) linv[r] = 1.0f / lacc[mq][r];
#pragma unroll
    for (int nd = 0; nd < 4; ++nd)
#pragma unroll
      for (int r = 0; r < 4; ++r) {
        const int pos = orow0 + mq * 16 + qd * 4 + r;
        const int d = nd * 16 + i;
        og[(size_t)(b * 1024 + pos) * 768 + h * 64 + d] =
            f2bf(oacc[mq][nd][r] * linv[r]);
      }
  }
}

// ---------------- proj GEMM: [16384,768] x [768,768]^T + b_eff -> f32 out ----
// Operand-swapped: reg r -> out col n, packed float4 stores. Dbuf staging.

__global__ __launch_bounds__(256) void k_gemm_proj(
    const unsigned short* __restrict__ A, const unsigned short* __restrict__ Bw,
    const float* __restrict__ bias, float* __restrict__ out) {
  __shared__ short la[2][128 * 32];
  __shared__ short lb[2][128 * 32];
  const int t = threadIdx.x;
  const int w = t >> 6, l = t & 63;
  const int i = l & 15, qd = l >> 4;
  const int wm = w >> 1, wn = w & 1;
  const int mblk = blockIdx.x, nblk = blockIdx.y;

  const unsigned short* Ab = A + (size_t)(mblk * 128) * 768;
  const unsigned short* Bb = Bw + (size_t)(nblk * 128) * 768;
  const int sr = l >> 2;
  const int sc = (l & 3) * 8;

  auto stage = [&](int bufn, int kb_) {
    const int k0 = kb_ * 32;
#pragma unroll
    for (int j = 0; j < 2; ++j) {
      const int row = w * 32 + j * 16 + sr;
      async16(Ab + row * 768 + k0 + sc, &la[bufn][(w * 32 + j * 16) * 32]);
      async16(Bb + row * 768 + k0 + sc, &lb[bufn][(w * 32 + j * 16) * 32]);
    }
  };

  stage(0, 0);

  f32x4 acc[4][4] = {};

  for (int kb_ = 0; kb_ < 24; ++kb_) {
    const int buf = kb_ & 1;
    __syncthreads();
    if (kb_ < 23) stage(buf ^ 1, kb_ + 1);
    s16x8 af[4], bf[4];
#pragma unroll
    for (int mi = 0; mi < 4; ++mi)
      af[mi] = *(const s16x8*)&la[buf][(wm * 64 + mi * 16 + i) * 32 + qd * 8];
#pragma unroll
    for (int ni = 0; ni < 4; ++ni)
      bf[ni] = *(const s16x8*)&lb[buf][(wn * 64 + ni * 16 + i) * 32 + qd * 8];
#pragma unroll
    for (int mi = 0; mi < 4; ++mi)
#pragma unroll
      for (int ni = 0; ni < 4; ++ni)
        acc[mi][ni] = mfma16(bf[ni], af[mi], acc[mi][ni]);  // swapped
  }

#pragma unroll
  for (int ni = 0; ni < 4; ++ni) {
    const int n0 = nblk * 128 + wn * 64 + ni * 16 + qd * 4;
    const float4 bv4 = *(const float4*)(bias + n0);
#pragma unroll
    for (int mi = 0; mi < 4; ++mi) {
      const int m = mblk * 128 + wm * 64 + mi * 16 + i;
      float4 o;
      o.x = acc[mi][ni][0] + bv4.x;
      o.y = acc[mi][ni][1] + bv4.y;
      o.z = acc[mi][ni][2] + bv4.z;
      o.w = acc[mi][ni][3] + bv4.w;
      *(float4*)&out[(size_t)m * 768 + n0] = o;
    }
  }
}

// ---------------- host ----------------

extern "C" void kernel_launch(void* const* d_in, const int* in_sizes, int n_in,
                              void* d_out, int out_size, void* d_ws, size_t ws_size,
                              hipStream_t stream) {
  const float* x = (const float*)d_in[0];
  const float* Wqkv = (const float*)d_in[1];
  const float* bqkv = (const float*)d_in[2];
  const float* Wp = (const float*)d_in[3];
  const float* bp = (const float*)d_in[4];
  const float* Aq = (const float*)d_in[5];
  const float* Bq = (const float*)d_in[6];
  const float* Ak = (const float*)d_in[7];
  const float* Bk = (const float*)d_in[8];
  const float* Av = (const float*)d_in[9];
  const float* Bv = (const float*)d_in[10];
  const float* Ao = (const float*)d_in[11];
  const float* Bo = (const float*)d_in[12];
  float* out = (float*)d_out;

  unsigned short* xb = (unsigned short*)d_ws;         // 16384*768
  unsigned short* wqkvb = xb + (size_t)MTOT * C;      // 2304*768
  unsigned short* wpeb = wqkvb + (size_t)N3 * C;      // 768*768
  unsigned short* qb = wpeb + (size_t)C * C;          // 192*1024*64
  unsigned short* kb = qb + (size_t)MTOT * C;
  unsigned short* vtb = kb + (size_t)MTOT * C;        // 192*64*1024 (transposed)
  float* Mbuf = (float*)(vtb + (size_t)MTOT * C);     // 16*768
  float* beff = Mbuf + 16 * 768;                      // 768
  unsigned short* ob = xb;  // alias: xb dead after QKV gemm

  k_prep_x<<<12288, 256, 0, stream>>>(x, xb);
  k_prep_wqkv<<<6912, 256, 0, stream>>>(Wqkv, Aq, Bq, Ak, Bk, Av, Bv, wqkvb);
  k_prep_M<<<16, 256, 0, stream>>>(Ao, Wp, Mbuf);
  k_prep_wpe<<<2304, 256, 0, stream>>>(Wp, Bo, Mbuf, wpeb);
  k_prep_beff<<<3, 256, 0, stream>>>(bp, Ao, Bo, beff);

  k_gemm_qkv_t<true><<<dim3(128, 12), 256, 0, stream>>>(xb, wqkvb, bqkv, 0,
                                                        qb, kb, vtb);
  k_gemm_qkv_t<false><<<dim3(128, 6), 256, 0, stream>>>(xb, wqkvb, bqkv, 12,
                                                        qb, kb, vtb);
  k_attn<<<dim3(192, 8), 256, 0, stream>>>(qb, kb, vtb, ob);
  k_gemm_proj<<<dim3(128, 6), 256, 0, stream>>>(ob, wpeb, beff, out);
}

// Round 5
// 344.726 us; speedup vs baseline: 1.2053x; 1.2053x over previous
//
#include <hip/hip_runtime.h>
#include <cmath>

// LoRAAttention, MI355X round 5.
//  - LoRA folded into effective weights (exact).
//  - QKV/proj GEMMs: dbuf async LDS staging, one barrier/K-iter, operand-swap
//    epilogues (packed stores).
//  - Attention: GEMM1 (16x16x32) C-layout feeds GEMM2 as 16x16x16 A-frags
//    DIRECTLY (C-layout == x16 A-layout identity) -> no zero-padded MFMA
//    halves; l-sum via ones-column x16 MFMA; native v_exp_f32.
//  - Preps fully parallelized (M: 192 blocks, beff: 1 block reduction).

#define DEVI __device__ __forceinline__

typedef float f32x4 __attribute__((ext_vector_type(4)));
typedef short s16x8 __attribute__((ext_vector_type(8)));
typedef short s16x4 __attribute__((ext_vector_type(4)));
typedef __bf16 b16x8 __attribute__((ext_vector_type(8)));
typedef unsigned int u32x4 __attribute__((ext_vector_type(4)));
typedef unsigned int u32x2 __attribute__((ext_vector_type(2)));

static constexpr int MTOT = 16384;   // B*N
static constexpr int C = 768;
static constexpr int N3 = 2304;

DEVI unsigned short f2bf(float x) {
  unsigned int u = __builtin_bit_cast(unsigned int, x);
  return (unsigned short)((u + 0x7FFFu + ((u >> 16) & 1u)) >> 16);
}

DEVI f32x4 mfma16(s16x8 a, s16x8 b, f32x4 c) {
  return __builtin_amdgcn_mfma_f32_16x16x32_bf16(
      __builtin_bit_cast(b16x8, a), __builtin_bit_cast(b16x8, b), c, 0, 0, 0);
}

#if __has_builtin(__builtin_amdgcn_mfma_f32_16x16x16bf16_1k)
#define HAVE_MFMA_X16 1
DEVI f32x4 mfma16h(s16x4 a, s16x4 b, f32x4 c) {
  return __builtin_amdgcn_mfma_f32_16x16x16bf16_1k(a, b, c, 0, 0, 0);
}
#else
#define HAVE_MFMA_X16 0
// fallback: zero-padded K=32 (both operands place data at k=qd*8+j, j<4)
DEVI f32x4 mfma16h(s16x4 a, s16x4 b, f32x4 c) {
  u32x2 au = __builtin_bit_cast(u32x2, a), bu = __builtin_bit_cast(u32x2, b);
  u32x4 a8 = {au[0], au[1], 0u, 0u}, b8 = {bu[0], bu[1], 0u, 0u};
  return mfma16(__builtin_bit_cast(s16x8, a8), __builtin_bit_cast(s16x8, b8), c);
}
#endif

DEVI void async16(const void* g, void* l) {
  __builtin_amdgcn_global_load_lds(
      (__attribute__((address_space(1))) void*)g,
      (__attribute__((address_space(3))) void*)l, 16, 0, 0);
}

// ---------------- prep kernels ----------------

__global__ __launch_bounds__(256) void k_prep_x(const float* __restrict__ x,
                                                unsigned short* __restrict__ xb) {
  int idx = (blockIdx.x * 256 + threadIdx.x) * 4;
  float4 v = *(const float4*)(x + idx);
  uint2 p;
  p.x = (unsigned int)f2bf(v.x) | ((unsigned int)f2bf(v.y) << 16);
  p.y = (unsigned int)f2bf(v.z) | ((unsigned int)f2bf(v.w) << 16);
  *(uint2*)(xb + idx) = p;
}

__global__ __launch_bounds__(256) void k_prep_wqkv(
    const float* __restrict__ W, const float* __restrict__ Aq,
    const float* __restrict__ Bq, const float* __restrict__ Ak,
    const float* __restrict__ Bk, const float* __restrict__ Av,
    const float* __restrict__ Bv, unsigned short* __restrict__ out) {
  int idx = blockIdx.x * 256 + threadIdx.x;  // n*768 + c
  int n = idx / 768, c = idx - n * 768;
  int s = n / 768, co = n - s * 768;
  const float* A = (s == 0) ? Aq : (s == 1) ? Ak : Av;
  const float* Bm = (s == 0) ? Bq : (s == 1) ? Bk : Bv;
  float acc = W[idx];
#pragma unroll
  for (int r = 0; r < 16; ++r) acc += Bm[co * 16 + r] * A[r * 768 + c];
  out[idx] = f2bf(acc);
}

// M[r][j] = sum_c Ao[r][c] * Wp[c][j]; grid (16 r, 12 jb), 256 thr
__global__ __launch_bounds__(256) void k_prep_M(const float* __restrict__ Ao,
                                                const float* __restrict__ Wp,
                                                float* __restrict__ M) {
  __shared__ float red[4][64];
  const int r = blockIdx.x, j0 = blockIdx.y * 64;
  const int jl = threadIdx.x & 63, cs = threadIdx.x >> 6;
  float acc = 0.f;
#pragma unroll 4
  for (int c = cs * 192; c < cs * 192 + 192; ++c)
    acc += Ao[r * 768 + c] * Wp[c * 768 + j0 + jl];
  red[cs][jl] = acc;
  __syncthreads();
  if (cs == 0)
    M[r * 768 + j0 + jl] = red[0][jl] + red[1][jl] + red[2][jl] + red[3][jl];
}

__global__ __launch_bounds__(256) void k_prep_wpe(const float* __restrict__ Wp,
                                                  const float* __restrict__ Bo,
                                                  const float* __restrict__ M,
                                                  unsigned short* __restrict__ out) {
  int idx = blockIdx.x * 256 + threadIdx.x;  // n*768 + j
  int n = idx / 768, j = idx - n * 768;
  float acc = Wp[idx];
#pragma unroll
  for (int r = 0; r < 16; ++r) acc += Bo[n * 16 + r] * M[r * 768 + j];
  out[idx] = f2bf(acc);
}

// single block: bv[r] = Ao[r]·bp, then beff = bp + Bo·bv
__global__ __launch_bounds__(256) void k_prep_beff(const float* __restrict__ bp,
                                                   const float* __restrict__ Ao,
                                                   const float* __restrict__ Bo,
                                                   float* __restrict__ beff) {
  __shared__ float red[256];
  __shared__ float bv[16];
  const int t = threadIdx.x;
  const int r = t >> 4, cs = t & 15;
  float a = 0.f;
#pragma unroll 4
  for (int c = cs * 48; c < cs * 48 + 48; ++c) a += Ao[r * 768 + c] * bp[c];
  red[t] = a;
  __syncthreads();
  if (cs == 0) {
    float s = 0.f;
#pragma unroll
    for (int k = 0; k < 16; ++k) s += red[r * 16 + k];
    bv[r] = s;
  }
  __syncthreads();
#pragma unroll
  for (int it = 0; it < 3; ++it) {
    const int n = it * 256 + t;
    float acc = bp[n];
#pragma unroll
    for (int r2 = 0; r2 < 16; ++r2) acc += Bo[n * 16 + r2] * bv[r2];
    beff[n] = acc;
  }
}

// ---------------- QKV GEMM: [16384,768] x [2304,768]^T -> q/k/vt bf16 --------
// Launched twice: SWAP=true for q/k n-blocks (packed d-stores), SWAP=false for
// v n-blocks (transposed [bh][d][pos] stores). One barrier per K-iter (dbuf).

template <bool SWAP>
__global__ __launch_bounds__(256) void k_gemm_qkv_t(
    const unsigned short* __restrict__ A, const unsigned short* __restrict__ Bw,
    const float* __restrict__ bias, int nblk0, unsigned short* __restrict__ qb,
    unsigned short* __restrict__ kb, unsigned short* __restrict__ vtb) {
  __shared__ short la[2][128 * 32];
  __shared__ short lb[2][128 * 32];
  const int t = threadIdx.x;
  const int w = t >> 6, l = t & 63;
  const int i = l & 15, qd = l >> 4;
  const int wm = w >> 1, wn = w & 1;
  const int mblk = blockIdx.x, nblk = nblk0 + blockIdx.y;

  const unsigned short* Ab = A + (size_t)(mblk * 128) * 768;
  const unsigned short* Bb = Bw + (size_t)(nblk * 128) * 768;
  const int sr = l >> 2;        // 0..15
  const int sc = (l & 3) * 8;   // 0,8,16,24

  auto stage = [&](int bufn, int kb_) {
    const int k0 = kb_ * 32;
#pragma unroll
    for (int j = 0; j < 2; ++j) {
      const int row = w * 32 + j * 16 + sr;
      async16(Ab + row * 768 + k0 + sc, &la[bufn][(w * 32 + j * 16) * 32]);
      async16(Bb + row * 768 + k0 + sc, &lb[bufn][(w * 32 + j * 16) * 32]);
    }
  };

  stage(0, 0);

  f32x4 acc[4][4] = {};

  for (int kb_ = 0; kb_ < 24; ++kb_) {
    const int buf = kb_ & 1;
    __syncthreads();
    if (kb_ < 23) stage(buf ^ 1, kb_ + 1);
    s16x8 af[4], bf[4];
#pragma unroll
    for (int mi = 0; mi < 4; ++mi)
      af[mi] = *(const s16x8*)&la[buf][(wm * 64 + mi * 16 + i) * 32 + qd * 8];
#pragma unroll
    for (int ni = 0; ni < 4; ++ni)
      bf[ni] = *(const s16x8*)&lb[buf][(wn * 64 + ni * 16 + i) * 32 + qd * 8];
#pragma unroll
    for (int mi = 0; mi < 4; ++mi)
#pragma unroll
      for (int ni = 0; ni < 4; ++ni) {
        if constexpr (SWAP)
          acc[mi][ni] = mfma16(bf[ni], af[mi], acc[mi][ni]);
        else
          acc[mi][ni] = mfma16(af[mi], bf[ni], acc[mi][ni]);
      }
  }

  const float c1 = 0.18033688011112042f;  // SCALE * log2(e)
  if constexpr (SWAP) {
    // q/k: lane i -> x-row (pos), reg r -> weight col (d): pack 4 d into 8B
#pragma unroll
    for (int ni = 0; ni < 4; ++ni) {
      const int n0 = nblk * 128 + wn * 64 + ni * 16 + qd * 4;
      const int s = n0 / 768;
      const int nrel = n0 - s * 768;
      const int h = nrel >> 6, d0 = nrel & 63;
      const float4 bv4 = *(const float4*)(bias + n0);
      unsigned short* dst = (s == 0) ? qb : kb;
      const float scl = (s == 0) ? c1 : 1.0f;
#pragma unroll
      for (int mi = 0; mi < 4; ++mi) {
        const int m = mblk * 128 + wm * 64 + mi * 16 + i;
        const int b = m >> 10, pos = m & 1023;
        uint2 pk;
        pk.x = (unsigned int)f2bf((acc[mi][ni][0] + bv4.x) * scl) |
               ((unsigned int)f2bf((acc[mi][ni][1] + bv4.y) * scl) << 16);
        pk.y = (unsigned int)f2bf((acc[mi][ni][2] + bv4.z) * scl) |
               ((unsigned int)f2bf((acc[mi][ni][3] + bv4.w) * scl) << 16);
        *(uint2*)&dst[(size_t)((b * 12 + h) * 1024 + pos) * 64 + d0] = pk;
      }
    }
  } else {
    // v: lane i -> weight col (d), reg r -> x-row (pos): transposed pack
#pragma unroll
    for (int ni = 0; ni < 4; ++ni) {
      const int n = nblk * 128 + wn * 64 + ni * 16 + i;
      const int nrel = n - 1536;
      const int h = nrel >> 6, d = nrel & 63;
      const float bvv = bias[n];
#pragma unroll
      for (int mi = 0; mi < 4; ++mi) {
        const int m0 = mblk * 128 + wm * 64 + mi * 16 + qd * 4;
        const int b = m0 >> 10, pos0 = m0 & 1023;
        uint2 pk;
        pk.x = (unsigned int)f2bf(acc[mi][ni][0] + bvv) |
               ((unsigned int)f2bf(acc[mi][ni][1] + bvv) << 16);
        pk.y = (unsigned int)f2bf(acc[mi][ni][2] + bvv) |
               ((unsigned int)f2bf(acc[mi][ni][3] + bvv) << 16);
        *(uint2*)&vtb[(size_t)((b * 12 + h) * 64 + d) * 1024 + pos0] = pk;
      }
    }
  }
}

// ---------------- flash attention ----------------
// grid: (192 bh, 8 q-tiles of 128 rows), 256 threads (4 waves x 32 q-rows).
// GEMM1 C-layout feeds x16 GEMM2 A-frags directly; l-sum via ones x16 MFMA.

__global__ __launch_bounds__(256, 4) void k_attn(
    const unsigned short* __restrict__ qg, const unsigned short* __restrict__ kg,
    const unsigned short* __restrict__ vtg, unsigned short* __restrict__ og) {
  __shared__ short k_lds[2][64 * 64];
  __shared__ short vt_lds[2][64 * 64];

  const int t = threadIdx.x;
  const int w = t >> 6, l = t & 63;
  const int i = l & 15, qd = l >> 4;
  const int ix7 = l & 7;
  const int bh = blockIdx.x;    // 0..191 (fastest -> same-bh tiles share XCD)
  const int qblk = blockIdx.y;  // 0..7
  const int h = bh % 12, b = bh / 12;

  const unsigned short* Qg = qg + (size_t)(bh * 1024 + qblk * 128) * 64;
  const unsigned short* Kg = kg + (size_t)bh * 1024 * 64;
  const unsigned short* Vtg = vtg + (size_t)bh * 64 * 1024;

  const int srl = l >> 3;            // row-local 0..7
  const int sgc = (l & 7) ^ srl;     // swizzled global chunk 0..7

  s16x8 qf[2][2];
#pragma unroll
  for (int nq = 0; nq < 2; ++nq)
#pragma unroll
    for (int k0 = 0; k0 < 2; ++k0)
      qf[nq][k0] =
          *(const s16x8*)(Qg + (w * 32 + nq * 16 + i) * 64 + k0 * 32 + qd * 8);

  auto stage = [&](int bufn, int tkv) {
#pragma unroll
    for (int it = 0; it < 2; ++it) {
      const int rbase = it * 32 + w * 8;
      async16(Kg + (size_t)(tkv * 64 + rbase + srl) * 64 + sgc * 8,
              &k_lds[bufn][rbase * 64]);
      async16(Vtg + (size_t)(rbase + srl) * 1024 + tkv * 64 + sgc * 8,
              &vt_lds[bufn][rbase * 64]);
    }
  };

  stage(0, 0);

  f32x4 oacc[2][4] = {};  // [mq][nd], C-layout (row=qrow, col=d)
  f32x4 lacc[2] = {};     // [mq], same layout
  const u32x2 ones_u = {0x3F803F80u, 0x3F803F80u};  // bf16 1.0 x4
  const s16x4 ones4 = __builtin_bit_cast(s16x4, ones_u);

  for (int tkv = 0; tkv < 16; ++tkv) {
    const int buf = tkv & 1;
    __syncthreads();
    if (tkv < 15) stage(buf ^ 1, tkv + 1);

#pragma unroll
    for (int mi = 0; mi < 4; ++mi) {
      // GEMM1: S^T[pos][qrow] tile (16 pos x 32 qrow) via K=32 MFMA
      f32x4 st[2] = {};
#pragma unroll
      for (int k0 = 0; k0 < 2; ++k0) {
        const s16x8 kf = *(const s16x8*)&k_lds[buf][(mi * 16 + i) * 64 +
                                                    (((k0 * 4 + qd) ^ ix7) * 8)];
        st[0] = mfma16(kf, qf[0][k0], st[0]);
        st[1] = mfma16(kf, qf[1][k0], st[1]);
      }

      // exp2 + truncating pack: C-layout regs r=0..3 become x16 A-frag k=qd*4+j
      s16x4 pa4[2];
#pragma unroll
      for (int mq = 0; mq < 2; ++mq) {
        unsigned int u0 = __builtin_bit_cast(
            unsigned int, __builtin_amdgcn_exp2f(st[mq][0]));
        unsigned int u1 = __builtin_bit_cast(
            unsigned int, __builtin_amdgcn_exp2f(st[mq][1]));
        unsigned int u2 = __builtin_bit_cast(
            unsigned int, __builtin_amdgcn_exp2f(st[mq][2]));
        unsigned int u3 = __builtin_bit_cast(
            unsigned int, __builtin_amdgcn_exp2f(st[mq][3]));
        u32x2 p;
        p[0] = __builtin_amdgcn_perm(u1, u0, 0x07060302u);
        p[1] = __builtin_amdgcn_perm(u3, u2, 0x07060302u);
        pa4[mq] = __builtin_bit_cast(s16x4, p);
      }

      // GEMM2 (x16, full utilization): O[qrow][d] += P[qrow][pos16(mi)]*V
#pragma unroll
      for (int nd = 0; nd < 4; ++nd) {
        const uint2 v = *(const uint2*)&vt_lds[buf][(nd * 16 + i) * 64 +
                                                    ((((mi * 2 + (qd >> 1)) ^ ix7) * 8) +
                                                     (qd & 1) * 4)];
        const s16x4 vf = __builtin_bit_cast(s16x4, v);
        oacc[0][nd] = mfma16h(pa4[0], vf, oacc[0][nd]);
        oacc[1][nd] = mfma16h(pa4[1], vf, oacc[1][nd]);
      }
      lacc[0] = mfma16h(pa4[0], ones4, lacc[0]);
      lacc[1] = mfma16h(pa4[1], ones4, lacc[1]);
    }
  }

  const int orow0 = qblk * 128 + w * 32;
#pragma unroll
  for (int mq = 0; mq < 2; ++mq) {
    float linv[4];
#pragma unroll
    for (int r = 0; r < 4; ++r) linv[r] = 1.0f / lacc[mq][r];
#pragma unroll
    for (int nd = 0; nd < 4; ++nd)
#pragma unroll
      for (int r = 0; r < 4; ++r) {
        const int pos = orow0 + mq * 16 + qd * 4 + r;
        const int d = nd * 16 + i;
        og[(size_t)(b * 1024 + pos) * 768 + h * 64 + d] =
            f2bf(oacc[mq][nd][r] * linv[r]);
      }
  }
}

// ---------------- proj GEMM: [16384,768] x [768,768]^T + b_eff -> f32 out ----
// Operand-swapped: reg r -> out col n, packed float4 stores. Dbuf staging.

__global__ __launch_bounds__(256) void k_gemm_proj(
    const unsigned short* __restrict__ A, const unsigned short* __restrict__ Bw,
    const float* __restrict__ bias, float* __restrict__ out) {
  __shared__ short la[2][128 * 32];
  __shared__ short lb[2][128 * 32];
  const int t = threadIdx.x;
  const int w = t >> 6, l = t & 63;
  const int i = l & 15, qd = l >> 4;
  const int wm = w >> 1, wn = w & 1;
  const int mblk = blockIdx.x, nblk = blockIdx.y;

  const unsigned short* Ab = A + (size_t)(mblk * 128) * 768;
  const unsigned short* Bb = Bw + (size_t)(nblk * 128) * 768;
  const int sr = l >> 2;
  const int sc = (l & 3) * 8;

  auto stage = [&](int bufn, int kb_) {
    const int k0 = kb_ * 32;
#pragma unroll
    for (int j = 0; j < 2; ++j) {
      const int row = w * 32 + j * 16 + sr;
      async16(Ab + row * 768 + k0 + sc, &la[bufn][(w * 32 + j * 16) * 32]);
      async16(Bb + row * 768 + k0 + sc, &lb[bufn][(w * 32 + j * 16) * 32]);
    }
  };

  stage(0, 0);

  f32x4 acc[4][4] = {};

  for (int kb_ = 0; kb_ < 24; ++kb_) {
    const int buf = kb_ & 1;
    __syncthreads();
    if (kb_ < 23) stage(buf ^ 1, kb_ + 1);
    s16x8 af[4], bf[4];
#pragma unroll
    for (int mi = 0; mi < 4; ++mi)
      af[mi] = *(const s16x8*)&la[buf][(wm * 64 + mi * 16 + i) * 32 + qd * 8];
#pragma unroll
    for (int ni = 0; ni < 4; ++ni)
      bf[ni] = *(const s16x8*)&lb[buf][(wn * 64 + ni * 16 + i) * 32 + qd * 8];
#pragma unroll
    for (int mi = 0; mi < 4; ++mi)
#pragma unroll
      for (int ni = 0; ni < 4; ++ni)
        acc[mi][ni] = mfma16(bf[ni], af[mi], acc[mi][ni]);  // swapped
  }

#pragma unroll
  for (int ni = 0; ni < 4; ++ni) {
    const int n0 = nblk * 128 + wn * 64 + ni * 16 + qd * 4;
    const float4 bv4 = *(const float4*)(bias + n0);
#pragma unroll
    for (int mi = 0; mi < 4; ++mi) {
      const int m = mblk * 128 + wm * 64 + mi * 16 + i;
      float4 o;
      o.x = acc[mi][ni][0] + bv4.x;
      o.y = acc[mi][ni][1] + bv4.y;
      o.z = acc[mi][ni][2] + bv4.z;
      o.w = acc[mi][ni][3] + bv4.w;
      *(float4*)&out[(size_t)m * 768 + n0] = o;
    }
  }
}

// ---------------- host ----------------

extern "C" void kernel_launch(void* const* d_in, const int* in_sizes, int n_in,
                              void* d_out, int out_size, void* d_ws, size_t ws_size,
                              hipStream_t stream) {
  const float* x = (const float*)d_in[0];
  const float* Wqkv = (const float*)d_in[1];
  const float* bqkv = (const float*)d_in[2];
  const float* Wp = (const float*)d_in[3];
  const float* bp = (const float*)d_in[4];
  const float* Aq = (const float*)d_in[5];
  const float* Bq = (const float*)d_in[6];
  const float* Ak = (const float*)d_in[7];
  const float* Bk = (const float*)d_in[8];
  const float* Av = (const float*)d_in[9];
  const float* Bv = (const float*)d_in[10];
  const float* Ao = (const float*)d_in[11];
  const float* Bo = (const float*)d_in[12];
  float* out = (float*)d_out;

  unsigned short* xb = (unsigned short*)d_ws;         // 16384*768
  unsigned short* wqkvb = xb + (size_t)MTOT * C;      // 2304*768
  unsigned short* wpeb = wqkvb + (size_t)N3 * C;      // 768*768
  unsigned short* qb = wpeb + (size_t)C * C;          // 192*1024*64
  unsigned short* kb = qb + (size_t)MTOT * C;
  unsigned short* vtb = kb + (size_t)MTOT * C;        // 192*64*1024 (transposed)
  float* Mbuf = (float*)(vtb + (size_t)MTOT * C);     // 16*768
  float* beff = Mbuf + 16 * 768;                      // 768
  unsigned short* ob = xb;  // alias: xb dead after QKV gemm

  k_prep_x<<<12288, 256, 0, stream>>>(x, xb);
  k_prep_wqkv<<<6912, 256, 0, stream>>>(Wqkv, Aq, Bq, Ak, Bk, Av, Bv, wqkvb);
  k_prep_M<<<dim3(16, 12), 256, 0, stream>>>(Ao, Wp, Mbuf);
  k_prep_wpe<<<2304, 256, 0, stream>>>(Wp, Bo, Mbuf, wpeb);
  k_prep_beff<<<1, 256, 0, stream>>>(bp, Ao, Bo, beff);

  k_gemm_qkv_t<true><<<dim3(128, 12), 256, 0, stream>>>(xb, wqkvb, bqkv, 0,
                                                        qb, kb, vtb);
  k_gemm_qkv_t<false><<<dim3(128, 6), 256, 0, stream>>>(xb, wqkvb, bqkv, 12,
                                                        qb, kb, vtb);
  k_attn<<<dim3(192, 8), 256, 0, stream>>>(qb, kb, vtb, ob);
  k_gemm_proj<<<dim3(128, 6), 256, 0, stream>>>(ob, wpeb, beff, out);
}